// Round 11
// baseline (658.630 us; speedup 1.0000x reference)
//
#include <hip/hip_runtime.h>
#include <hip/hip_bf16.h>
#include <math.h>

// Problem constants (fixed by setup_inputs)
#define BB 16
#define CC 192
#define TS 2048
#define TT 512
#define KK 384   // 2*CC

// d_out float offsets
#define OFF_PATH 0
#define OFF_DUR  (16777216)
#define OFF_LOGW (OFF_DUR + 8192)
#define OFF_MEXP (OFF_LOGW + 8192)
#define OFF_LEXP (OFF_MEXP + 6291456)
#define OFF_TMASK (OFF_LEXP + 6291456)
#define OFF_SMASK (OFF_TMASK + 8192)

#define NEGCF (-1e9f)
#define GSTR (TT*4)          // floats per t-group in ncT = 2048

// ---------------------------------------------------------------------------
// prep: per (b,u): s = exp(-2 logs), Bmat rows {m*s, s}, avec = nc1+nc4,
// plus text_mask / spec_mask outputs.
__global__ __launch_bounds__(512) void vits_prep(
    const float* __restrict__ m_p, const float* __restrict__ logs_p,
    const int* __restrict__ spec_len, const int* __restrict__ text_len,
    float* __restrict__ Bmat, float* __restrict__ avec,
    float* __restrict__ tmask, float* __restrict__ smask)
{
    const int b = blockIdx.x;
    const int u = threadIdx.x;
    const float C0 = -0.91893853320467274178f; // -0.5*log(2*pi)
    float a_acc = 0.f;
    for (int c = 0; c < CC; ++c) {
        float lg = logs_p[((size_t)b*CC + c)*TT + u];
        float mm = m_p[((size_t)b*CC + c)*TT + u];
        float s  = expf(-2.f*lg);
        float ms = mm * s;
        Bmat[((size_t)b*KK + 2*c    )*TT + u] = ms;  // pairs with z      -> neg_cent3
        Bmat[((size_t)b*KK + 2*c + 1)*TT + u] = s;   // pairs with -.5z^2 -> neg_cent2
        a_acc += C0 - lg - 0.5f*mm*ms;               // nc1 + nc4 terms
    }
    avec[b*TT + u] = a_acc;
    tmask[b*TT + u] = (u < text_len[b]) ? 1.f : 0.f;
    for (int t = u; t < TS; t += TT)
        smask[b*TS + t] = (t < spec_len[b]) ? 1.f : 0.f;
}

// ---------------------------------------------------------------------------
// gemm: ncT[b][g][u][k] = avec[b][u] + sum_k X[*][t=4g+k] * Bmat[*][u]
// (time-blocked transposed output so the DP can load 4 timesteps per instr)
__global__ __launch_bounds__(256) void vits_gemm(
    const float* __restrict__ z, const float* __restrict__ Bmat,
    const float* __restrict__ avec, float* __restrict__ ncT)
{
    const int b  = blockIdx.z;
    const int t0 = blockIdx.y * 64;
    const int u0 = blockIdx.x * 64;
    __shared__ float As[16][68];
    __shared__ float Bs[16][68];
    const int tid = threadIdx.x;
    const int tx = tid & 15, ty = tid >> 4;
    float acc[4][4] = {};
    const float* zb = z    + (size_t)b * CC * TS;
    const float* Bb = Bmat + (size_t)b * KK * TT;
    for (int kc = 0; kc < KK/16; ++kc) {
        {
            int c_l = tid >> 5;            // 0..7
            int t_l = (tid & 31) * 2;
            const float* zp = zb + (size_t)(kc*8 + c_l)*TS + t0 + t_l;
            float2 zv = *(const float2*)zp;
            float2 z1 = make_float2(zv.x, zv.y);
            float2 z2 = make_float2(-0.5f*zv.x*zv.x, -0.5f*zv.y*zv.y);
            *(float2*)&As[2*c_l  ][t_l] = z1;
            *(float2*)&As[2*c_l+1][t_l] = z2;
            int k_l = tid >> 4;            // 0..15
            int u_l = (tid & 15) * 4;
            const float* bp = Bb + (size_t)(kc*16 + k_l)*TT + u0 + u_l;
            *(float4*)&Bs[k_l][u_l] = *(const float4*)bp;
        }
        __syncthreads();
        #pragma unroll
        for (int kk = 0; kk < 16; ++kk) {
            float4 av = *(const float4*)&As[kk][ty*4];
            float4 bv = *(const float4*)&Bs[kk][tx*4];
            float aa[4] = {av.x, av.y, av.z, av.w};
            float bb[4] = {bv.x, bv.y, bv.z, bv.w};
            #pragma unroll
            for (int i = 0; i < 4; ++i)
                #pragma unroll
                for (int jj = 0; jj < 4; ++jj)
                    acc[i][jj] += aa[i]*bb[jj];
        }
        __syncthreads();
    }
    float4 a4 = *(const float4*)(avec + b*TT + u0 + tx*4);
    float ab[4] = {a4.x, a4.y, a4.z, a4.w};
    const int g = (t0 >> 2) + ty;                 // t-group (t = 4g+i)
    float* outp = ncT + (((size_t)b*(TS/4) + g)*TT + u0 + tx*4) * 4;
    #pragma unroll
    for (int jj = 0; jj < 4; ++jj) {
        float4 o;
        o.x = acc[0][jj] + ab[jj];
        o.y = acc[1][jj] + ab[jj];
        o.z = acc[2][jj] + ab[jj];
        o.w = acc[3][jj] + ab[jj];
        *(float4*)(outp + jj*4) = o;              // 4 consecutive 16B blocks/thread
    }
}

// ---------------------------------------------------------------------------
// DPP full-wave rotate-by-1: lane n <- lane (n-1)&63 (wave_ror:1 = 0x13C).
__device__ __forceinline__ float dpp_ror1_f32(float v) {
    union { float f; int i; } u, r;
    u.f = v;
    r.i = __builtin_amdgcn_update_dpp(0, u.i, 0x13C, 0xF, 0xF, false);
    return r.f;
}

// ---------------------------------------------------------------------------
// dp: forward Viterbi (f32), trapezoidal in-thread tiling, 1 wave per batch.
// Lane L holds state s[12] = q[t-1] for cols [8L-4 .. 8L+7]: s[0..3] = ghost
// copies of the left lane's last 4 cols, s[4..11] = own auth cols 8L..8L+7.
// Per 4-step block: 38 lane-local updates (cone widths 11,10,9,8 — all
// updates at step k depend only on step k-1 state, so there is NO in-step
// cross-column chain), then ONE cross-lane exchange (4 DPP ror1 shipping
// s[8..11] -> next block's s[0..3]). The expensive dependent cross-lane op
// (~280cyc measured across R4-R10 regardless of DPP/shfl/bpermute flavor)
// thus lands on the serial chain once per 4 steps instead of every step.
// Loads: 12 float4 (4 timesteps x 12 cols) per block from wave-uniform base
// + per-lane constant byte offsets, double-buffered in named registers.
// dirs bit-packed per own col along t (32-t windows), bank-swizzled.
#define DIRS(j,w) dirs[((j)<<6) | ((w) ^ ((j) & 31))]

__global__ __launch_bounds__(64, 1) void vits_dp(
    const float* __restrict__ ncT,
    const int* __restrict__ spec_len, const int* __restrict__ text_len,
    float* __restrict__ dur, float* __restrict__ logw, int* __restrict__ jt)
{
    __shared__ unsigned int dirs[TT*(TS/32)];   // 128 KB (swizzled)
    __shared__ int Tr[TT + 1];                  // 2 KB

    const int tid  = threadIdx.x;
    const int lane = tid & 63;
    const int b = blockIdx.x;
    const int SL = spec_len[b], TL = text_len[b];
    const bool l0 = (lane == 0);
    const int col0 = lane << 3;                  // first own col = 8L

    // state: s[i] = q(t-1)[8L-4+i]; ghosts i=0..3, own i=4..11
    float s[12];
    #pragma unroll
    for (int i = 0; i < 12; ++i) s[i] = NEGCF;
    if (l0) s[4] = 0.0f;                         // q(-1)[0] = 0

    unsigned int bits[8] = {0,0,0,0,0,0,0,0};

    // per-lane constant byte offsets for the 12 cols (clamped; lane0's
    // ghost cols clamp to col0 -> finite junk, pinned to NEG anyway)
    int coff[12];
    #pragma unroll
    for (int i = 0; i < 12; ++i) {
        int c = col0 - 4 + i;
        if (c < 0) c = 0;
        coff[i] = c << 4;                        // *16 bytes (float4 per col)
    }
    const char* ncbase = (const char*)ncT + (size_t)b*(TS/4)*GSTR*4;

    float4 bufA[12], bufB[12];
    #pragma unroll
    for (int i = 0; i < 12; ++i)
        bufA[i] = *(const float4*)(ncbase + coff[i]);   // group 0

    int tb = 0, blk = 0;
    const int nblk = SL >> 2;

#define BLOCKSTEP(BUF, OBUF) do {                                            \
        {   /* prefetch next group */                                        \
            int gn = blk + 1; if (gn > TS/4 - 1) gn = TS/4 - 1;              \
            const char* bpn = ncbase + (size_t)gn * (GSTR*4);                \
            _Pragma("unroll")                                                \
            for (int i = 0; i < 12; ++i)                                     \
                OBUF[i] = *(const float4*)(bpn + coff[i]);                   \
        }                                                                    \
        _Pragma("unroll")                                                    \
        for (int k = 0; k < 4; ++k) {                                        \
            _Pragma("unroll")                                                \
            for (int i = 11; i >= 1; --i) {                                  \
                if (i <= k) continue;   /* cone: step k updates i>k */       \
                float f = ((const float*)&BUF[i])[k];                        \
                if (i >= 4) {                                                \
                    bool d = (s[i-1] >= s[i]);                               \
                    bits[i-4] = (bits[i-4] << 1) | (unsigned)d;              \
                    s[i] = f + fmaxf(s[i-1], s[i]);                          \
                } else {                                                     \
                    s[i] = f + fmaxf(s[i-1], s[i]);                          \
                }                                                            \
            }                                                                \
        }                                                                    \
        {   /* cross-lane exchange: next block's ghosts */                   \
            float g0_ = dpp_ror1_f32(s[8]);                                  \
            float g1_ = dpp_ror1_f32(s[9]);                                  \
            float g2_ = dpp_ror1_f32(s[10]);                                 \
            float g3_ = dpp_ror1_f32(s[11]);                                 \
            s[0] = l0 ? NEGCF : g0_;                                         \
            s[1] = l0 ? NEGCF : g1_;                                         \
            s[2] = l0 ? NEGCF : g2_;                                         \
            s[3] = l0 ? NEGCF : g3_;                                         \
        }                                                                    \
        if ((tb & 28) == 28) {  /* window of 32 steps complete */            \
            _Pragma("unroll")                                                \
            for (int m = 0; m < 8; ++m) {                                    \
                DIRS(col0 + m, tb >> 5) = bits[m];                           \
                bits[m] = 0;                                                 \
            }                                                                \
        }                                                                    \
        tb += 4; ++blk;                                                      \
    } while (0)

    for (; blk + 2 <= nblk; ) {
        BLOCKSTEP(bufA, bufB);
        BLOCKSTEP(bufB, bufA);
    }
    if (blk < nblk) BLOCKSTEP(bufA, bufB);

    // tail (SL & 3 steps): direct loads, runtime-bounded small loop
    const int rem = SL & 3;
    if (rem) {
        float4 tbuf[12];
        const char* bpt = ncbase + (size_t)(SL >> 2) * (GSTR*4);
        #pragma unroll
        for (int i = 0; i < 12; ++i)
            tbuf[i] = *(const float4*)(bpt + coff[i]);
        for (int k = 0; k < rem; ++k) {
            #pragma unroll
            for (int i = 11; i >= 1; --i) {
                if (i <= k) continue;
                float f = ((const float*)&tbuf[i])[k];
                if (i >= 4) {
                    bool d = (s[i-1] >= s[i]);
                    bits[i-4] = (bits[i-4] << 1) | (unsigned)d;
                    s[i] = f + fmaxf(s[i-1], s[i]);
                } else {
                    s[i] = f + fmaxf(s[i-1], s[i]);
                }
            }
        }
    }
    if (SL & 31) {
        int w = SL >> 5, r = SL & 31;
        #pragma unroll
        for (int m = 0; m < 8; ++m)
            DIRS(col0 + m, w) = bits[m] << (32 - r);
    }
    __syncthreads();

    for (int i = tid; i <= TT; i += 64) Tr[i] = 0;
    __syncthreads();

    if (tid == 0) {
        Tr[TL] = SL;
        int j = TL - 1, tc = SL - 1;
        // Tr[j] = first frame aligned to text index j (transition time)
        while (j > 0 && tc >= 0) {
            int w = tc >> 5;
            int bcur = 31 - (tc & 31);
            unsigned int W = DIRS(j, w) & (0xFFFFFFFFu << bcur);
            if (W) {
                int bp = __ffs(W) - 1;          // lowest set bit >= bcur
                int tp = (w << 5) + 31 - bp;    // = largest t' <= tc with d=1
                Tr[j] = tp;
                --j;
                tc = tp - 1;
            } else {
                if (w == 0) break;
                tc = (w << 5) - 1;
            }
        }
    }
    __syncthreads();

    for (int u = tid; u < TT; u += 64) {
        float dv = (u < TL) ? (float)(Tr[u+1] - Tr[u]) : 0.0f;
        dur[b*TT + u] = dv;
        logw[b*TT + u] = (u < TL) ? logf(dv + 1e-6f) : 0.0f;
    }
    // jt: range-fill [Tr[u], Tr[u+1]) -> u
    for (int u = 0; u < TL; ++u) {
        int t1 = Tr[u+1];
        for (int t = Tr[u] + tid; t < t1; t += 64) jt[b*TS + t] = u;
    }
    for (int t = SL + tid; t < TS; t += 64) jt[b*TS + t] = -1;
}

// ---------------------------------------------------------------------------
// path: path[b][t][u] = (u == jt[b][t]) ? 1 : 0   (float4-vectorized)
__global__ void vits_path(const int* __restrict__ jt, float4* __restrict__ path)
{
    int idx = blockIdx.x*blockDim.x + threadIdx.x;
    const int total = BB*TS*(TT/4);
    for (; idx < total; idx += gridDim.x*blockDim.x) {
        int u4 = idx & (TT/4 - 1);
        int bt = idx >> 7;
        int j = jt[bt];
        float4 v = make_float4(0.f,0.f,0.f,0.f);
        int r = j - (u4 << 2);
        if (r >= 0 && r < 4) ((float*)&v)[r] = 1.f;
        path[idx] = v;
    }
}

// ---------------------------------------------------------------------------
// m/logs expansion: out[b][c][t] = (jt>=0) ? src[b][c][jt] : 0
__global__ void vits_mlexp(const int* __restrict__ jt,
    const float* __restrict__ m_p, const float* __restrict__ logs_p,
    float4* __restrict__ mexp, float4* __restrict__ lexp)
{
    int idx = blockIdx.x*blockDim.x + threadIdx.x;
    const int total = BB*CC*(TS/4);
    for (; idx < total; idx += gridDim.x*blockDim.x) {
        int t4 = idx & (TS/4 - 1);
        int bc = idx >> 9;
        int b = bc / CC;
        int4 jv = *(const int4*)(jt + b*TS + (t4 << 2));
        const float* mrow = m_p    + (size_t)bc*TT;
        const float* lrow = logs_p + (size_t)bc*TT;
        float4 mv, lv;
        mv.x = (jv.x >= 0) ? mrow[jv.x] : 0.f;  lv.x = (jv.x >= 0) ? lrow[jv.x] : 0.f;
        mv.y = (jv.y >= 0) ? mrow[jv.y] : 0.f;  lv.y = (jv.y >= 0) ? lrow[jv.y] : 0.f;
        mv.z = (jv.z >= 0) ? mrow[jv.z] : 0.f;  lv.z = (jv.z >= 0) ? lrow[jv.z] : 0.f;
        mv.w = (jv.w >= 0) ? mrow[jv.w] : 0.f;  lv.w = (jv.w >= 0) ? lrow[jv.w] : 0.f;
        mexp[idx] = mv;
        lexp[idx] = lv;
    }
}

// ---------------------------------------------------------------------------
extern "C" void kernel_launch(void* const* d_in, const int* in_sizes, int n_in,
                              void* d_out, int out_size, void* d_ws, size_t ws_size,
                              hipStream_t stream) {
    const float* z_p      = (const float*)d_in[0];
    const float* m_p      = (const float*)d_in[1];
    const float* logs_p   = (const float*)d_in[2];
    const int*   spec_len = (const int*)d_in[3];
    const int*   text_len = (const int*)d_in[4];
    float* out = (float*)d_out;

    float* Bmat = (float*)d_ws;                  // [B][384][512] f32 = 12.6 MB
    float* avec = Bmat + (size_t)BB*KK*TT;       // [B][512]
    int*   jt   = (int*)(avec + BB*TT);          // [B][2048]

    float* path  = out + OFF_PATH;   // doubles as ncT staging ([B][TS/4][TT][4])
    float* dur   = out + OFF_DUR;
    float* logw  = out + OFF_LOGW;
    float* mexp  = out + OFF_MEXP;
    float* lexp  = out + OFF_LEXP;
    float* tmask = out + OFF_TMASK;
    float* smask = out + OFF_SMASK;

    vits_prep<<<BB, 512, 0, stream>>>(m_p, logs_p, spec_len, text_len,
                                      Bmat, avec, tmask, smask);
    vits_gemm<<<dim3(TT/64, TS/64, BB), 256, 0, stream>>>(z_p, Bmat, avec, path);
    vits_dp<<<BB, 64, 0, stream>>>(path, spec_len, text_len, dur, logw, jt);
    vits_path<<<2048, 256, 0, stream>>>(jt, (float4*)path);
    vits_mlexp<<<2048, 256, 0, stream>>>(jt, m_p, logs_p, (float4*)mexp, (float4*)lexp);
}

// Round 12
// 461.207 us; speedup vs baseline: 1.4281x; 1.4281x over previous
//
#include <hip/hip_runtime.h>
#include <hip/hip_bf16.h>
#include <math.h>

// Problem constants (fixed by setup_inputs)
#define BB 16
#define CC 192
#define TS 2048
#define TT 512
#define KK 384   // 2*CC

// d_out float offsets
#define OFF_PATH 0
#define OFF_DUR  (16777216)
#define OFF_LOGW (OFF_DUR + 8192)
#define OFF_MEXP (OFF_LOGW + 8192)
#define OFF_LEXP (OFF_MEXP + 6291456)
#define OFF_TMASK (OFF_LEXP + 6291456)
#define OFF_SMASK (OFF_TMASK + 8192)

#define NEGCF (-1e9f)

// ---------------------------------------------------------------------------
// prep (parallelized: 256 blocks = full chip; was 16 blocks -> 16 CUs).
// Block (uc, b): 512 threads = 16 c-groups x 32 u-lanes; c-loop 12 iters;
// LDS tree-reduce partial a_acc over the 16 c-groups per u.
__global__ __launch_bounds__(512) void vits_prep(
    const float* __restrict__ m_p, const float* __restrict__ logs_p,
    const int* __restrict__ spec_len, const int* __restrict__ text_len,
    float* __restrict__ Bmat, float* __restrict__ avec,
    float* __restrict__ tmask, float* __restrict__ smask)
{
    const int uc = blockIdx.x;          // 0..15 (u-chunk of 32)
    const int b  = blockIdx.y;
    const int tid = threadIdx.x;
    const int ul = tid & 31;
    const int cg = tid >> 5;            // 0..15
    const int u = uc*32 + ul;
    const float C0 = -0.91893853320467274178f; // -0.5*log(2*pi)
    float a_acc = 0.f;
    for (int c = cg; c < CC; c += 16) {
        float lg = logs_p[((size_t)b*CC + c)*TT + u];
        float mm = m_p[((size_t)b*CC + c)*TT + u];
        float s  = expf(-2.f*lg);
        float ms = mm * s;
        Bmat[((size_t)b*KK + 2*c    )*TT + u] = ms;  // pairs with z      -> neg_cent3
        Bmat[((size_t)b*KK + 2*c + 1)*TT + u] = s;   // pairs with -.5z^2 -> neg_cent2
        a_acc += C0 - lg - 0.5f*mm*ms;               // nc1 + nc4 terms
    }
    __shared__ float red[16][33];
    red[cg][ul] = a_acc;
    __syncthreads();
    #pragma unroll
    for (int s = 8; s > 0; s >>= 1) {
        if (cg < s) red[cg][ul] += red[cg + s][ul];
        __syncthreads();
    }
    if (cg == 0) {
        avec[b*TT + u] = red[0][ul];
        tmask[b*TT + u] = (u < text_len[b]) ? 1.f : 0.f;
    }
    if (tid < 128) {
        int t = uc*128 + tid;
        smask[b*TS + t] = (t < spec_len[b]) ? 1.f : 0.f;
    }
}

// ---------------------------------------------------------------------------
// gemm: nc[b][t][u] = avec[b][u] + sum_k X[k][t] * Bmat[k][u]
// X[2c][t] = z[b][c][t], X[2c+1][t] = -0.5*z^2. 64x64 tile, 4x4 microtile.
__global__ __launch_bounds__(256) void vits_gemm(
    const float* __restrict__ z, const float* __restrict__ Bmat,
    const float* __restrict__ avec, float* __restrict__ out)
{
    const int b  = blockIdx.z;
    const int t0 = blockIdx.y * 64;
    const int u0 = blockIdx.x * 64;
    __shared__ float As[16][68];
    __shared__ float Bs[16][68];
    const int tid = threadIdx.x;
    const int tx = tid & 15, ty = tid >> 4;
    float acc[4][4] = {};
    const float* zb = z    + (size_t)b * CC * TS;
    const float* Bb = Bmat + (size_t)b * KK * TT;
    for (int kc = 0; kc < KK/16; ++kc) {
        {
            int c_l = tid >> 5;            // 0..7
            int t_l = (tid & 31) * 2;
            const float* zp = zb + (size_t)(kc*8 + c_l)*TS + t0 + t_l;
            float2 zv = *(const float2*)zp;
            float2 z1 = make_float2(zv.x, zv.y);
            float2 z2 = make_float2(-0.5f*zv.x*zv.x, -0.5f*zv.y*zv.y);
            *(float2*)&As[2*c_l  ][t_l] = z1;
            *(float2*)&As[2*c_l+1][t_l] = z2;
            int k_l = tid >> 4;            // 0..15
            int u_l = (tid & 15) * 4;
            const float* bp = Bb + (size_t)(kc*16 + k_l)*TT + u0 + u_l;
            *(float4*)&Bs[k_l][u_l] = *(const float4*)bp;
        }
        __syncthreads();
        #pragma unroll
        for (int kk = 0; kk < 16; ++kk) {
            float4 av = *(const float4*)&As[kk][ty*4];
            float4 bv = *(const float4*)&Bs[kk][tx*4];
            float aa[4] = {av.x, av.y, av.z, av.w};
            float bb[4] = {bv.x, bv.y, bv.z, bv.w};
            #pragma unroll
            for (int i = 0; i < 4; ++i)
                #pragma unroll
                for (int jj = 0; jj < 4; ++jj)
                    acc[i][jj] += aa[i]*bb[jj];
        }
        __syncthreads();
    }
    float4 a4 = *(const float4*)(avec + b*TT + u0 + tx*4);
    float ab[4] = {a4.x, a4.y, a4.z, a4.w};
    #pragma unroll
    for (int i = 0; i < 4; ++i) {
        float4 o;
        o.x = acc[i][0] + ab[0];
        o.y = acc[i][1] + ab[1];
        o.z = acc[i][2] + ab[2];
        o.w = acc[i][3] + ab[3];
        *(float4*)(out + ((size_t)b*TS + t0 + ty*4 + i)*TT + u0 + tx*4) = o;
    }
}

// ---------------------------------------------------------------------------
// DPP full-wave rotate-by-1: lane n <- lane (n-1)&63 (wave_ror:1 = 0x13C).
__device__ __forceinline__ float dpp_ror1_f32(float v) {
    union { float f; int i; } u, r;
    u.f = v;
    r.i = __builtin_amdgcn_update_dpp(0, u.i, 0x13C, 0xF, 0xF, false);
    return r.f;
}

// ---------------------------------------------------------------------------
// dp: forward Viterbi (f32), 16-wave ghost-zone tiling (best-known, R7).
// Wave w: lanes 32-63 own auth columns w*32..w*32+31; lanes 0-31 ghost-copy
// the left wave's columns. col = w*32+lane-32; wave_ror1 provides col-1.
// Ghost lane 0 takes junk; corruption moves 1 lane/step and reaches auth
// only after 33 steps > 32-step refresh cadence.
// dirs bit-packed per auth col along t (32-t windows), bank-swizzled.
#define DIRS(j,w) dirs[((j)<<6) | ((w) ^ ((j) & 31))]
#define RING 16

__global__ __launch_bounds__(1024, 1) void vits_dp(
    const float* __restrict__ nc,
    const int* __restrict__ spec_len, const int* __restrict__ text_len,
    float* __restrict__ dur, float* __restrict__ logw, int* __restrict__ jt)
{
    __shared__ unsigned int dirs[TT*(TS/32)];   // 128 KB (swizzled)
    __shared__ float qrow[TT];                  // 2 KB
    __shared__ int Tr[TT + 1];                  // 2 KB

    const int tid  = threadIdx.x;
    const int lane = tid & 63;
    const int wid  = tid >> 6;
    const int b = blockIdx.x;
    const int SL = spec_len[b], TL = text_len[b];
    const int col = (wid << 5) + lane - 32;      // auth if lane>=32, ghost else
    const bool auth = (lane >= 32);
    const bool w0g  = (wid == 0) && (lane < 32); // pinned-NEG ghost lanes
    const int colL = (col < 0) ? 0 : col;

    float q = (col == 0) ? 0.0f : NEGCF;
    unsigned int bits = 0;

    const float* ncb = nc + (size_t)b*TS*TT + colL;

    // register prefetch ring, distance RING (static indices via full unroll)
    float pf[RING];
    #pragma unroll
    for (int i = 0; i < RING; ++i) pf[i] = ncb[(size_t)i*TT];
    const float* pcur = ncb + (size_t)RING*TT;   // next row to fetch

    int tb = 0;
    for (; tb + 32 <= SL; tb += 32) {
        #pragma unroll
        for (int s = 0; s < 32; ++s) {
            const int t = tb + s;
            float f = pf[s & (RING-1)];
            pf[s & (RING-1)] = *pcur;            // row t+RING (junk past SL; never consumed)
            pcur += TT;

            float qp = dpp_ror1_f32(q);          // lane l <- q[col-1]
            bool d = (qp >= q);                  // ref: q_shift >= q
            bits = (bits << 1) | (unsigned)d;
            float qn = f + fmaxf(qp, q);
            q = w0g ? NEGCF : qn;

            if (s == 31) {
                if (auth) {
                    DIRS(col, t >> 5) = bits;
                    qrow[col] = q;
                }
                bits = 0;
                __syncthreads();
                if (!auth && wid != 0) q = qrow[col];   // ghost refresh
                __syncthreads();
            }
        }
    }
    // tail (SL & 31 steps)
    for (int t = tb; t < SL; ++t) {
        float f = ncb[(size_t)t*TT];
        float qp = dpp_ror1_f32(q);
        bool d = (qp >= q);
        bits = (bits << 1) | (unsigned)d;
        float qn = f + fmaxf(qp, q);
        q = w0g ? NEGCF : qn;
    }
    if (SL & 31) {
        int w = SL >> 5, r = SL & 31;
        if (auth) DIRS(col, w) = bits << (32 - r);
    }
    __syncthreads();

    for (int i = tid; i <= TT; i += 1024) Tr[i] = 0;
    __syncthreads();

    if (tid == 0) {
        Tr[TL] = SL;
        int j = TL - 1, tc = SL - 1;
        // Tr[j] = first frame aligned to text index j (transition time)
        while (j > 0 && tc >= 0) {
            int w = tc >> 5;
            int bcur = 31 - (tc & 31);
            unsigned int W = DIRS(j, w) & (0xFFFFFFFFu << bcur);
            if (W) {
                int bp = __ffs(W) - 1;          // lowest set bit >= bcur
                int tp = (w << 5) + 31 - bp;    // = largest t' <= tc with d=1
                Tr[j] = tp;
                --j;
                tc = tp - 1;
            } else {
                if (w == 0) break;
                tc = (w << 5) - 1;
            }
        }
    }
    __syncthreads();

    for (int u = tid; u < TT; u += 1024) {
        float dv = (u < TL) ? (float)(Tr[u+1] - Tr[u]) : 0.0f;
        dur[b*TT + u] = dv;
        logw[b*TT + u] = (u < TL) ? logf(dv + 1e-6f) : 0.0f;
    }
    // jt: range-fill [Tr[u], Tr[u+1]) -> u
    for (int u = 0; u < TL; ++u) {
        int t1 = Tr[u+1];
        for (int t = Tr[u] + tid; t < t1; t += 1024) jt[b*TS + t] = u;
    }
    for (int t = SL + tid; t < TS; t += 1024) jt[b*TS + t] = -1;
}

// ---------------------------------------------------------------------------
// path: path[b][t][u] = (u == jt[b][t]) ? 1 : 0   (float4-vectorized)
__global__ void vits_path(const int* __restrict__ jt, float4* __restrict__ path)
{
    int idx = blockIdx.x*blockDim.x + threadIdx.x;
    const int total = BB*TS*(TT/4);
    for (; idx < total; idx += gridDim.x*blockDim.x) {
        int u4 = idx & (TT/4 - 1);
        int bt = idx >> 7;
        int j = jt[bt];
        float4 v = make_float4(0.f,0.f,0.f,0.f);
        int r = j - (u4 << 2);
        if (r >= 0 && r < 4) ((float*)&v)[r] = 1.f;
        path[idx] = v;
    }
}

// ---------------------------------------------------------------------------
// m/logs expansion: out[b][c][t] = (jt>=0) ? src[b][c][jt] : 0
__global__ void vits_mlexp(const int* __restrict__ jt,
    const float* __restrict__ m_p, const float* __restrict__ logs_p,
    float4* __restrict__ mexp, float4* __restrict__ lexp)
{
    int idx = blockIdx.x*blockDim.x + threadIdx.x;
    const int total = BB*CC*(TS/4);
    for (; idx < total; idx += gridDim.x*blockDim.x) {
        int t4 = idx & (TS/4 - 1);
        int bc = idx >> 9;
        int b = bc / CC;
        int4 jv = *(const int4*)(jt + b*TS + (t4 << 2));
        const float* mrow = m_p    + (size_t)bc*TT;
        const float* lrow = logs_p + (size_t)bc*TT;
        float4 mv, lv;
        mv.x = (jv.x >= 0) ? mrow[jv.x] : 0.f;  lv.x = (jv.x >= 0) ? lrow[jv.x] : 0.f;
        mv.y = (jv.y >= 0) ? mrow[jv.y] : 0.f;  lv.y = (jv.y >= 0) ? lrow[jv.y] : 0.f;
        mv.z = (jv.z >= 0) ? mrow[jv.z] : 0.f;  lv.z = (jv.z >= 0) ? lrow[jv.z] : 0.f;
        mv.w = (jv.w >= 0) ? mrow[jv.w] : 0.f;  lv.w = (jv.w >= 0) ? lrow[jv.w] : 0.f;
        mexp[idx] = mv;
        lexp[idx] = lv;
    }
}

// ---------------------------------------------------------------------------
extern "C" void kernel_launch(void* const* d_in, const int* in_sizes, int n_in,
                              void* d_out, int out_size, void* d_ws, size_t ws_size,
                              hipStream_t stream) {
    const float* z_p      = (const float*)d_in[0];
    const float* m_p      = (const float*)d_in[1];
    const float* logs_p   = (const float*)d_in[2];
    const int*   spec_len = (const int*)d_in[3];
    const int*   text_len = (const int*)d_in[4];
    float* out = (float*)d_out;

    float* Bmat = (float*)d_ws;                  // [B][384][512] f32 = 12.6 MB
    float* avec = Bmat + (size_t)BB*KK*TT;       // [B][512]
    int*   jt   = (int*)(avec + BB*TT);          // [B][2048]

    float* path  = out + OFF_PATH;   // doubles as neg_cent staging
    float* dur   = out + OFF_DUR;
    float* logw  = out + OFF_LOGW;
    float* mexp  = out + OFF_MEXP;
    float* lexp  = out + OFF_LEXP;
    float* tmask = out + OFF_TMASK;
    float* smask = out + OFF_SMASK;

    vits_prep<<<dim3(16, BB), 512, 0, stream>>>(m_p, logs_p, spec_len, text_len,
                                                Bmat, avec, tmask, smask);
    vits_gemm<<<dim3(TT/64, TS/64, BB), 256, 0, stream>>>(z_p, Bmat, avec, path);
    vits_dp<<<BB, 1024, 0, stream>>>(path, spec_len, text_len, dur, logw, jt);
    vits_path<<<2048, 256, 0, stream>>>(jt, (float4*)path);
    vits_mlexp<<<2048, 256, 0, stream>>>(jt, m_p, logs_p, (float4*)mexp, (float4*)lexp);
}

// Round 13
// 440.803 us; speedup vs baseline: 1.4942x; 1.0463x over previous
//
#include <hip/hip_runtime.h>
#include <hip/hip_bf16.h>
#include <math.h>

// Problem constants (fixed by setup_inputs)
#define BB 16
#define CC 192
#define TS 2048
#define TT 512
#define KK 384   // 2*CC

// d_out float offsets
#define OFF_PATH 0
#define OFF_DUR  (16777216)
#define OFF_LOGW (OFF_DUR + 8192)
#define OFF_MEXP (OFF_LOGW + 8192)
#define OFF_LEXP (OFF_MEXP + 6291456)
#define OFF_TMASK (OFF_LEXP + 6291456)
#define OFF_SMASK (OFF_TMASK + 8192)

#define NEGCF (-1e9f)

// ---------------------------------------------------------------------------
// prep (parallelized: 256 blocks = full chip).
// Block (uc, b): 512 threads = 16 c-groups x 32 u-lanes; c-loop 12 iters;
// LDS tree-reduce partial a_acc over the 16 c-groups per u.
__global__ __launch_bounds__(512) void vits_prep(
    const float* __restrict__ m_p, const float* __restrict__ logs_p,
    const int* __restrict__ spec_len, const int* __restrict__ text_len,
    float* __restrict__ Bmat, float* __restrict__ avec,
    float* __restrict__ tmask, float* __restrict__ smask)
{
    const int uc = blockIdx.x;          // 0..15 (u-chunk of 32)
    const int b  = blockIdx.y;
    const int tid = threadIdx.x;
    const int ul = tid & 31;
    const int cg = tid >> 5;            // 0..15
    const int u = uc*32 + ul;
    const float C0 = -0.91893853320467274178f; // -0.5*log(2*pi)
    float a_acc = 0.f;
    for (int c = cg; c < CC; c += 16) {
        float lg = logs_p[((size_t)b*CC + c)*TT + u];
        float mm = m_p[((size_t)b*CC + c)*TT + u];
        float s  = expf(-2.f*lg);
        float ms = mm * s;
        Bmat[((size_t)b*KK + 2*c    )*TT + u] = ms;  // pairs with z      -> neg_cent3
        Bmat[((size_t)b*KK + 2*c + 1)*TT + u] = s;   // pairs with -.5z^2 -> neg_cent2
        a_acc += C0 - lg - 0.5f*mm*ms;               // nc1 + nc4 terms
    }
    __shared__ float red[16][33];
    red[cg][ul] = a_acc;
    __syncthreads();
    #pragma unroll
    for (int s = 8; s > 0; s >>= 1) {
        if (cg < s) red[cg][ul] += red[cg + s][ul];
        __syncthreads();
    }
    if (cg == 0) {
        avec[b*TT + u] = red[0][ul];
        tmask[b*TT + u] = (u < text_len[b]) ? 1.f : 0.f;
    }
    if (tid < 128) {
        int t = uc*128 + tid;
        smask[b*TS + t] = (t < spec_len[b]) ? 1.f : 0.f;
    }
}

// ---------------------------------------------------------------------------
// gemm: nc[b][t][u] = avec[b][u] + sum_k X[k][t] * Bmat[k][u]
// X[2c][t] = z[b][c][t], X[2c+1][t] = -0.5*z^2.
// 128x128 tile (halves traffic vs 64x64), BK=8 panel, 8x8 microtile split
// into 4+4 halves (LDS reads at tx*4 / tx*4+64 -> 2-way bank alias = free).
// Register prefetch of next panel overlaps global latency with compute.
// Per-output k-accumulation order identical to the 64x64 version ->
// bit-identical nc -> DP decisions unchanged.
__global__ __launch_bounds__(256) void vits_gemm(
    const float* __restrict__ z, const float* __restrict__ Bmat,
    const float* __restrict__ avec, float* __restrict__ out)
{
    const int b  = blockIdx.z;
    const int t0 = blockIdx.y * 128;
    const int u0 = blockIdx.x * 128;
    __shared__ float As[8][128];
    __shared__ float Bs[8][128];
    const int tid = threadIdx.x;
    const int tx = tid & 15, ty = tid >> 4;
    float acc[8][8] = {};
    const float* zb = z    + (size_t)b * CC * TS;
    const float* Bb = Bmat + (size_t)b * KK * TT;

    const int c_l = tid >> 6;           // 0..3 (A: 4 z-channels/panel)
    const int t_l = (tid & 63) * 2;     // 0..126
    const int k_b = tid >> 5;           // 0..7 (B: 8 rows/panel)
    const int u_l = (tid & 31) * 4;     // 0..124

    float2 zr = *(const float2*)(zb + (size_t)c_l*TS + t0 + t_l);
    float4 br = *(const float4*)(Bb + (size_t)k_b*TT + u0 + u_l);

    for (int kc = 0; kc < KK/8; ++kc) {
        *(float2*)&As[2*c_l  ][t_l] = make_float2(zr.x, zr.y);
        *(float2*)&As[2*c_l+1][t_l] = make_float2(-0.5f*zr.x*zr.x, -0.5f*zr.y*zr.y);
        *(float4*)&Bs[k_b][u_l] = br;
        __syncthreads();
        if (kc + 1 < KK/8) {            // prefetch next panel (overlaps compute)
            zr = *(const float2*)(zb + (size_t)((kc+1)*4 + c_l)*TS + t0 + t_l);
            br = *(const float4*)(Bb + (size_t)((kc+1)*8 + k_b)*TT + u0 + u_l);
        }
        #pragma unroll
        for (int k = 0; k < 8; ++k) {
            float4 a0 = *(const float4*)&As[k][ty*4];
            float4 a1 = *(const float4*)&As[k][ty*4 + 64];
            float4 b0 = *(const float4*)&Bs[k][tx*4];
            float4 b1 = *(const float4*)&Bs[k][tx*4 + 64];
            float aa[8] = {a0.x,a0.y,a0.z,a0.w,a1.x,a1.y,a1.z,a1.w};
            float bb[8] = {b0.x,b0.y,b0.z,b0.w,b1.x,b1.y,b1.z,b1.w};
            #pragma unroll
            for (int i = 0; i < 8; ++i)
                #pragma unroll
                for (int j = 0; j < 8; ++j)
                    acc[i][j] += aa[i]*bb[j];
        }
        __syncthreads();
    }

    float4 ab0 = *(const float4*)(avec + b*TT + u0 + tx*4);
    float4 ab1 = *(const float4*)(avec + b*TT + u0 + tx*4 + 64);
    float ab[8] = {ab0.x,ab0.y,ab0.z,ab0.w,ab1.x,ab1.y,ab1.z,ab1.w};
    #pragma unroll
    for (int i = 0; i < 8; ++i) {
        int tt = t0 + ((i < 4) ? (ty*4 + i) : (64 + ty*4 + (i-4)));
        float* orow = out + (size_t)((size_t)b*TS + tt)*TT + u0;
        float4 o0, o1;
        o0.x = acc[i][0] + ab[0]; o0.y = acc[i][1] + ab[1];
        o0.z = acc[i][2] + ab[2]; o0.w = acc[i][3] + ab[3];
        o1.x = acc[i][4] + ab[4]; o1.y = acc[i][5] + ab[5];
        o1.z = acc[i][6] + ab[6]; o1.w = acc[i][7] + ab[7];
        *(float4*)(orow + tx*4)      = o0;
        *(float4*)(orow + tx*4 + 64) = o1;
    }
}

// ---------------------------------------------------------------------------
// DPP full-wave rotate-by-1: lane n <- lane (n-1)&63 (wave_ror:1 = 0x13C).
__device__ __forceinline__ float dpp_ror1_f32(float v) {
    union { float f; int i; } u, r;
    u.f = v;
    r.i = __builtin_amdgcn_update_dpp(0, u.i, 0x13C, 0xF, 0xF, false);
    return r.f;
}

// ---------------------------------------------------------------------------
// dp: forward Viterbi (f32), 16-wave ghost-zone tiling (best-known, R7).
// Wave w: lanes 32-63 own auth columns w*32..w*32+31; lanes 0-31 ghost-copy
// the left wave's columns. col = w*32+lane-32; wave_ror1 provides col-1.
// Ghost lane 0 takes junk; corruption moves 1 lane/step and reaches auth
// only after 33 steps > 32-step refresh cadence.
// dirs bit-packed per auth col along t (32-t windows), bank-swizzled.
#define DIRS(j,w) dirs[((j)<<6) | ((w) ^ ((j) & 31))]
#define RING 16

__global__ __launch_bounds__(1024, 1) void vits_dp(
    const float* __restrict__ nc,
    const int* __restrict__ spec_len, const int* __restrict__ text_len,
    float* __restrict__ dur, float* __restrict__ logw, int* __restrict__ jt)
{
    __shared__ unsigned int dirs[TT*(TS/32)];   // 128 KB (swizzled)
    __shared__ float qrow[TT];                  // 2 KB
    __shared__ int Tr[TT + 1];                  // 2 KB

    const int tid  = threadIdx.x;
    const int lane = tid & 63;
    const int wid  = tid >> 6;
    const int b = blockIdx.x;
    const int SL = spec_len[b], TL = text_len[b];
    const int col = (wid << 5) + lane - 32;      // auth if lane>=32, ghost else
    const bool auth = (lane >= 32);
    const bool w0g  = (wid == 0) && (lane < 32); // pinned-NEG ghost lanes
    const int colL = (col < 0) ? 0 : col;

    float q = (col == 0) ? 0.0f : NEGCF;
    unsigned int bits = 0;

    const float* ncb = nc + (size_t)b*TS*TT + colL;

    // register prefetch ring, distance RING (static indices via full unroll)
    float pf[RING];
    #pragma unroll
    for (int i = 0; i < RING; ++i) pf[i] = ncb[(size_t)i*TT];
    const float* pcur = ncb + (size_t)RING*TT;   // next row to fetch

    int tb = 0;
    for (; tb + 32 <= SL; tb += 32) {
        #pragma unroll
        for (int s = 0; s < 32; ++s) {
            const int t = tb + s;
            float f = pf[s & (RING-1)];
            pf[s & (RING-1)] = *pcur;            // row t+RING (junk past SL; never consumed)
            pcur += TT;

            float qp = dpp_ror1_f32(q);          // lane l <- q[col-1]
            bool d = (qp >= q);                  // ref: q_shift >= q
            bits = (bits << 1) | (unsigned)d;
            float qn = f + fmaxf(qp, q);
            q = w0g ? NEGCF : qn;

            if (s == 31) {
                if (auth) {
                    DIRS(col, t >> 5) = bits;
                    qrow[col] = q;
                }
                bits = 0;
                __syncthreads();
                if (!auth && wid != 0) q = qrow[col];   // ghost refresh
                __syncthreads();
            }
        }
    }
    // tail (SL & 31 steps)
    for (int t = tb; t < SL; ++t) {
        float f = ncb[(size_t)t*TT];
        float qp = dpp_ror1_f32(q);
        bool d = (qp >= q);
        bits = (bits << 1) | (unsigned)d;
        float qn = f + fmaxf(qp, q);
        q = w0g ? NEGCF : qn;
    }
    if (SL & 31) {
        int w = SL >> 5, r = SL & 31;
        if (auth) DIRS(col, w) = bits << (32 - r);
    }
    __syncthreads();

    for (int i = tid; i <= TT; i += 1024) Tr[i] = 0;
    __syncthreads();

    if (tid == 0) {
        Tr[TL] = SL;
        int j = TL - 1, tc = SL - 1;
        // Tr[j] = first frame aligned to text index j (transition time)
        while (j > 0 && tc >= 0) {
            int w = tc >> 5;
            int bcur = 31 - (tc & 31);
            unsigned int W = DIRS(j, w) & (0xFFFFFFFFu << bcur);
            if (W) {
                int bp = __ffs(W) - 1;          // lowest set bit >= bcur
                int tp = (w << 5) + 31 - bp;    // = largest t' <= tc with d=1
                Tr[j] = tp;
                --j;
                tc = tp - 1;
            } else {
                if (w == 0) break;
                tc = (w << 5) - 1;
            }
        }
    }
    __syncthreads();

    for (int u = tid; u < TT; u += 1024) {
        float dv = (u < TL) ? (float)(Tr[u+1] - Tr[u]) : 0.0f;
        dur[b*TT + u] = dv;
        logw[b*TT + u] = (u < TL) ? logf(dv + 1e-6f) : 0.0f;
    }
    // jt: range-fill [Tr[u], Tr[u+1]) -> u
    for (int u = 0; u < TL; ++u) {
        int t1 = Tr[u+1];
        for (int t = Tr[u] + tid; t < t1; t += 1024) jt[b*TS + t] = u;
    }
    for (int t = SL + tid; t < TS; t += 1024) jt[b*TS + t] = -1;
}

// ---------------------------------------------------------------------------
// path: path[b][t][u] = (u == jt[b][t]) ? 1 : 0   (float4-vectorized)
__global__ void vits_path(const int* __restrict__ jt, float4* __restrict__ path)
{
    int idx = blockIdx.x*blockDim.x + threadIdx.x;
    const int total = BB*TS*(TT/4);
    for (; idx < total; idx += gridDim.x*blockDim.x) {
        int u4 = idx & (TT/4 - 1);
        int bt = idx >> 7;
        int j = jt[bt];
        float4 v = make_float4(0.f,0.f,0.f,0.f);
        int r = j - (u4 << 2);
        if (r >= 0 && r < 4) ((float*)&v)[r] = 1.f;
        path[idx] = v;
    }
}

// ---------------------------------------------------------------------------
// m/logs expansion: out[b][c][t] = (jt>=0) ? src[b][c][jt] : 0
__global__ void vits_mlexp(const int* __restrict__ jt,
    const float* __restrict__ m_p, const float* __restrict__ logs_p,
    float4* __restrict__ mexp, float4* __restrict__ lexp)
{
    int idx = blockIdx.x*blockDim.x + threadIdx.x;
    const int total = BB*CC*(TS/4);
    for (; idx < total; idx += gridDim.x*blockDim.x) {
        int t4 = idx & (TS/4 - 1);
        int bc = idx >> 9;
        int b = bc / CC;
        int4 jv = *(const int4*)(jt + b*TS + (t4 << 2));
        const float* mrow = m_p    + (size_t)bc*TT;
        const float* lrow = logs_p + (size_t)bc*TT;
        float4 mv, lv;
        mv.x = (jv.x >= 0) ? mrow[jv.x] : 0.f;  lv.x = (jv.x >= 0) ? lrow[jv.x] : 0.f;
        mv.y = (jv.y >= 0) ? mrow[jv.y] : 0.f;  lv.y = (jv.y >= 0) ? lrow[jv.y] : 0.f;
        mv.z = (jv.z >= 0) ? mrow[jv.z] : 0.f;  lv.z = (jv.z >= 0) ? lrow[jv.z] : 0.f;
        mv.w = (jv.w >= 0) ? mrow[jv.w] : 0.f;  lv.w = (jv.w >= 0) ? lrow[jv.w] : 0.f;
        mexp[idx] = mv;
        lexp[idx] = lv;
    }
}

// ---------------------------------------------------------------------------
extern "C" void kernel_launch(void* const* d_in, const int* in_sizes, int n_in,
                              void* d_out, int out_size, void* d_ws, size_t ws_size,
                              hipStream_t stream) {
    const float* z_p      = (const float*)d_in[0];
    const float* m_p      = (const float*)d_in[1];
    const float* logs_p   = (const float*)d_in[2];
    const int*   spec_len = (const int*)d_in[3];
    const int*   text_len = (const int*)d_in[4];
    float* out = (float*)d_out;

    float* Bmat = (float*)d_ws;                  // [B][384][512] f32 = 12.6 MB
    float* avec = Bmat + (size_t)BB*KK*TT;       // [B][512]
    int*   jt   = (int*)(avec + BB*TT);          // [B][2048]

    float* path  = out + OFF_PATH;   // doubles as neg_cent staging
    float* dur   = out + OFF_DUR;
    float* logw  = out + OFF_LOGW;
    float* mexp  = out + OFF_MEXP;
    float* lexp  = out + OFF_LEXP;
    float* tmask = out + OFF_TMASK;
    float* smask = out + OFF_SMASK;

    vits_prep<<<dim3(16, BB), 512, 0, stream>>>(m_p, logs_p, spec_len, text_len,
                                                Bmat, avec, tmask, smask);
    vits_gemm<<<dim3(TT/128, TS/128, BB), 256, 0, stream>>>(z_p, Bmat, avec, path);
    vits_dp<<<BB, 1024, 0, stream>>>(path, spec_len, text_len, dur, logw, jt);
    vits_path<<<2048, 256, 0, stream>>>(jt, (float4*)path);
    vits_mlexp<<<2048, 256, 0, stream>>>(jt, m_p, logs_p, (float4*)mexp, (float4*)lexp);
}